// Round 2
// baseline (1047.840 us; speedup 1.0000x reference)
//
#include <hip/hip_runtime.h>

typedef _Float16 f16;
typedef _Float16 f16x8 __attribute__((ext_vector_type(8)));
typedef _Float16 f16x4 __attribute__((ext_vector_type(4)));
typedef float f32x4 __attribute__((ext_vector_type(4)));

#define SEQ    2048
#define NMODEL 4096
#define DHEAD  128
#define HHEADS 32
#define MCACHE 4096

// ---------------------------------------------------------------- helpers
__device__ __forceinline__ void glds16(const f16* g, f16* l) {
  __builtin_amdgcn_global_load_lds((const __attribute__((address_space(1))) void*)g,
                                   (__attribute__((address_space(3))) void*)l,
                                   16, 0, 0);
}

// ---------------------------------------------------------------- cast f32 -> f16 (8 elems/thread)
__global__ __launch_bounds__(256) void cast_kernel(const float* __restrict__ in,
                                                   f16* __restrict__ out, long n8) {
  long i = (long)blockIdx.x * 256 + threadIdx.x;
  const long stride = (long)gridDim.x * 256;
  for (; i < n8; i += stride) {
    const float4* p = (const float4*)(in + i * 8);
    const float4 a = p[0], b = p[1];
    f16x8 h;
    h[0] = (f16)a.x; h[1] = (f16)a.y; h[2] = (f16)a.z; h[3] = (f16)a.w;
    h[4] = (f16)b.x; h[5] = (f16)b.y; h[6] = (f16)b.z; h[7] = (f16)b.w;
    *(f16x8*)(out + i * 8) = h;
  }
}

// ---------------------------------------------------------------- tiled transpose-cast: in f32 [R][C] -> out f16 [C][R]
__global__ __launch_bounds__(256) void transpose_cast_kernel(const float* __restrict__ in,
                                                             f16* __restrict__ out,
                                                             int R, int C,
                                                             long inBatch, long outBatch) {
  __shared__ float tile[64][65];
  const int tid = threadIdx.x;
  const int r0 = blockIdx.x * 64, c0 = blockIdx.y * 64;
  in  += (size_t)blockIdx.z * inBatch;
  out += (size_t)blockIdx.z * outBatch;
#pragma unroll
  for (int p = 0; p < 4; ++p) {
    const int row = p * 16 + (tid >> 4);
    const int q = tid & 15;
    const float4 v = *(const float4*)&in[(size_t)(r0 + row) * C + c0 + q * 4];
    tile[row][q * 4 + 0] = v.x; tile[row][q * 4 + 1] = v.y;
    tile[row][q * 4 + 2] = v.z; tile[row][q * 4 + 3] = v.w;
  }
  __syncthreads();
#pragma unroll
  for (int p = 0; p < 4; ++p) {
    const int crow = p * 16 + (tid >> 4);
    const int q = tid & 15;
    f16x4 hv;
    hv[0] = (f16)tile[q * 4 + 0][crow];
    hv[1] = (f16)tile[q * 4 + 1][crow];
    hv[2] = (f16)tile[q * 4 + 2][crow];
    hv[3] = (f16)tile[q * 4 + 3][crow];
    *(f16x4*)&out[(size_t)(c0 + crow) * R + r0 + q * 4] = hv;
  }
}

// ---------------------------------------------------------------- fp16 GEMM, m97 structure (128x128 tile, BK=32, 4 waves)
// A: [Ma][4096] f16 (k-major), B: [Nb][4096] f16 (k-major). D[m][n] = sum_k A[m][k]*B[n][k]
// MODE 0: out = Qh[s][n]            (A = Xh, m=s; B = Wt, n = model col)
// MODE 1: out = KCh[h][P+s][d]      (A = Xh; n = h*128+d)
// MODE 2: out = VTh[h][d][P+s]      (A = Wt, m = model col = h*128+d; B = Xh, n = s)
template<int MODE>
__global__ __launch_bounds__(256) void gemm_kernel(const f16* __restrict__ A,
                                                   const f16* __restrict__ B,
                                                   f16* __restrict__ out,
                                                   const int* __restrict__ Pptr) {
  __shared__ __align__(16) f16 Ash[128 * 32];
  __shared__ __align__(16) f16 Bsh[128 * 32];
  const int tid = threadIdx.x;
  const int lane = tid & 63;
  const int w = tid >> 6;
  const int wr = w >> 1, wc = w & 1;
  const int c = lane & 15, g = lane >> 4;
  const size_t rowA = (size_t)blockIdx.x * 128;
  const size_t rowB = (size_t)blockIdx.y * 128;

  f32x4 acc[4][4] = {};

  const int r0 = tid >> 2;            // 0..63
  const int qq = tid & 3;             // 16B chunk within a 64B row
  const int r1 = r0 + 64;

  for (int kt = 0; kt < NMODEL / 32; ++kt) {
    const int k0 = kt * 32;
    __syncthreads();
    glds16(&A[(rowA + r0) * NMODEL + k0 + qq * 8], &Ash[(size_t)tid * 8]);
    glds16(&A[(rowA + r1) * NMODEL + k0 + qq * 8], &Ash[(size_t)(tid + 256) * 8]);
    glds16(&B[(rowB + r0) * NMODEL + k0 + qq * 8], &Bsh[(size_t)tid * 8]);
    glds16(&B[(rowB + r1) * NMODEL + k0 + qq * 8], &Bsh[(size_t)(tid + 256) * 8]);
    __syncthreads();
    f16x8 af[4], bf[4];
#pragma unroll
    for (int f = 0; f < 4; ++f)
      af[f] = *(const f16x8*)&Ash[(wr * 64 + f * 16 + c) * 32 + g * 8];
#pragma unroll
    for (int f = 0; f < 4; ++f)
      bf[f] = *(const f16x8*)&Bsh[(wc * 64 + f * 16 + c) * 32 + g * 8];
#pragma unroll
    for (int i = 0; i < 4; ++i)
#pragma unroll
      for (int j = 0; j < 4; ++j)
        acc[i][j] = __builtin_amdgcn_mfma_f32_16x16x32_f16(af[i], bf[j], acc[i][j], 0, 0, 0);
  }

  int Pv = 0;
  if (MODE != 0) Pv = *Pptr;
#pragma unroll
  for (int i = 0; i < 4; ++i)
#pragma unroll
    for (int j = 0; j < 4; ++j)
#pragma unroll
      for (int r = 0; r < 4; ++r) {
        const size_t mi = rowA + wr * 64 + i * 16 + g * 4 + r;
        const size_t ni = rowB + wc * 64 + j * 16 + c;
        const f16 v = (f16)acc[i][j][r];
        if (MODE == 0) {
          out[mi * NMODEL + ni] = v;
        } else if (MODE == 1) {
          const size_t h = ni >> 7, d = ni & 127;
          out[(h * MCACHE + (size_t)Pv + mi) * DHEAD + d] = v;
        } else {
          const size_t h = mi >> 7, d = mi & 127;
          out[(h * DHEAD + d) * MCACHE + (size_t)Pv + ni] = v;
        }
      }
}

// ---------------------------------------------------------------- flash attention
// Qh [S][4096] f16, KC [H][M][D] f16, VT [H][D][M] f16, out f32 flat [H][S][D]
__global__ __launch_bounds__(256) void attn_kernel(const f16* __restrict__ Qh,
                                                   const f16* __restrict__ KC,
                                                   const f16* __restrict__ VT,
                                                   float* __restrict__ out) {
  __shared__ __align__(16) f16 Ks[64 * 128];      // [m][d], XOR-swizzled
  __shared__ __align__(16) f16 Vs[128 * 64];      // [d][m], XOR-swizzled
  __shared__ __align__(16) f16 Ps[4][32 * 64];    // per-wave [s][m], XOR-swizzled
  const int tid = threadIdx.x;
  const int lane = tid & 63, w = tid >> 6;
  const int c = lane & 15, g = lane >> 4;
  const int h = blockIdx.y;
  const int q0 = blockIdx.x * 128 + w * 32;

  // Q held in registers as A-fragments: qf[sf][kg] -> rows q0+sf*16+c, d = kg*32 + g*8..+7
  f16x8 qf[2][4];
#pragma unroll
  for (int sf = 0; sf < 2; ++sf)
#pragma unroll
    for (int kg = 0; kg < 4; ++kg)
      qf[sf][kg] = *(const f16x8*)&Qh[(size_t)(q0 + sf * 16 + c) * NMODEL + h * DHEAD + kg * 32 + g * 8];

  f32x4 acc[2][8] = {};
  float mrow[2][4], lrow[2][4];
#pragma unroll
  for (int sf = 0; sf < 2; ++sf)
#pragma unroll
    for (int i = 0; i < 4; ++i) { mrow[sf][i] = -1e30f; lrow[sf][i] = 0.f; }

  const f16* Kb = KC + (size_t)h * MCACHE * DHEAD;
  const f16* Vb = VT + (size_t)h * DHEAD * MCACHE;
  char* KsB = (char*)Ks;
  char* VsB = (char*)Vs;
  char* PsB = (char*)&Ps[w][0];

  for (int kv = 0; kv < MCACHE / 64; ++kv) {
    __syncthreads();
    // stage K tile [64][128]
#pragma unroll
    for (int p = 0; p < 4; ++p) {
      const int slot = p * 256 + tid;
      const int r = slot >> 4, dq = slot & 15;
      const f16x8 v = *(const f16x8*)&Kb[(size_t)(kv * 64 + r) * DHEAD + dq * 8];
      *(f16x8*)(KsB + ((r * 256 + dq * 16) ^ ((r & 7) << 4))) = v;
    }
    // stage V tile [128][64] (already transposed in VT)
#pragma unroll
    for (int p = 0; p < 4; ++p) {
      const int slot = p * 256 + tid;
      const int d = slot >> 3, mq = slot & 7;
      const f16x8 v = *(const f16x8*)&Vb[(size_t)d * MCACHE + kv * 64 + mq * 8];
      *(f16x8*)(VsB + ((d * 128 + mq * 16) ^ ((d & 7) << 4))) = v;
    }
    __syncthreads();

    // QK^T: sc[sf][mf], rows = q-local, cols = kv-local
    f32x4 sc[2][4] = {};
#pragma unroll
    for (int mf = 0; mf < 4; ++mf) {
      const int mr = mf * 16 + c;
#pragma unroll
      for (int kg = 0; kg < 4; ++kg) {
        const f16x8 kb = *(const f16x8*)(KsB + ((mr * 256 + kg * 64 + g * 16) ^ ((mr & 7) << 4)));
        sc[0][mf] = __builtin_amdgcn_mfma_f32_16x16x32_f16(qf[0][kg], kb, sc[0][mf], 0, 0, 0);
        sc[1][mf] = __builtin_amdgcn_mfma_f32_16x16x32_f16(qf[1][kg], kb, sc[1][mf], 0, 0, 0);
      }
    }

    // online softmax (wave-parallel; rows live on 16-lane groups)
#pragma unroll
    for (int sf = 0; sf < 2; ++sf)
#pragma unroll
      for (int i = 0; i < 4; ++i) {
        float pm = fmaxf(fmaxf(sc[sf][0][i], sc[sf][1][i]), fmaxf(sc[sf][2][i], sc[sf][3][i]));
#pragma unroll
        for (int m = 1; m < 16; m <<= 1) pm = fmaxf(pm, __shfl_xor(pm, m));
        const float mold = mrow[sf][i];
        const float mnew = fmaxf(mold, pm);
        const float scale = __expf(mold - mnew);
        float rs = 0.f;
#pragma unroll
        for (int mf = 0; mf < 4; ++mf) {
          const float e = __expf(sc[sf][mf][i] - mnew);
          sc[sf][mf][i] = e;
          rs += e;
        }
#pragma unroll
        for (int m = 1; m < 16; m <<= 1) rs += __shfl_xor(rs, m);
        lrow[sf][i] = lrow[sf][i] * scale + rs;
        mrow[sf][i] = mnew;
#pragma unroll
        for (int df = 0; df < 8; ++df) acc[sf][df][i] *= scale;
      }

    // P -> per-wave LDS (swizzled), fp16
#pragma unroll
    for (int sf = 0; sf < 2; ++sf)
#pragma unroll
      for (int i = 0; i < 4; ++i) {
        const int r = sf * 16 + g * 4 + i;
#pragma unroll
        for (int mf = 0; mf < 4; ++mf) {
          const int cc = mf * 16 + c;
          *(f16*)(PsB + ((r * 128 + cc * 2) ^ ((r & 7) << 4))) = (f16)sc[sf][mf][i];
        }
      }

    // PV: acc[sf][df] += P[sf] * V
#pragma unroll
    for (int kg2 = 0; kg2 < 2; ++kg2) {
      f16x8 pa[2];
#pragma unroll
      for (int sf = 0; sf < 2; ++sf) {
        const int pr = sf * 16 + c;
        pa[sf] = *(const f16x8*)(PsB + ((pr * 128 + kg2 * 64 + g * 16) ^ ((pr & 7) << 4)));
      }
#pragma unroll
      for (int df = 0; df < 8; ++df) {
        const int dr = df * 16 + c;
        const f16x8 vb = *(const f16x8*)(VsB + ((dr * 128 + kg2 * 64 + g * 16) ^ ((dr & 7) << 4)));
        acc[0][df] = __builtin_amdgcn_mfma_f32_16x16x32_f16(pa[0], vb, acc[0][df], 0, 0, 0);
        acc[1][df] = __builtin_amdgcn_mfma_f32_16x16x32_f16(pa[1], vb, acc[1][df], 0, 0, 0);
      }
    }
  }

  // epilogue: out[h][s][d] = acc / l   (raw [H,S,D] flat layout == reference reshape)
#pragma unroll
  for (int sf = 0; sf < 2; ++sf)
#pragma unroll
    for (int i = 0; i < 4; ++i) {
      const float inv = 1.0f / lrow[sf][i];
      const int srow = q0 + sf * 16 + g * 4 + i;
#pragma unroll
      for (int df = 0; df < 8; ++df)
        out[((size_t)h * SEQ + srow) * DHEAD + df * 16 + c] = acc[sf][df][i] * inv;
    }
}

// ---------------------------------------------------------------- launch
extern "C" void kernel_launch(void* const* d_in, const int* in_sizes, int n_in,
                              void* d_out, int out_size, void* d_ws, size_t ws_size,
                              hipStream_t stream) {
  (void)in_sizes; (void)n_in; (void)out_size;
  const float* X  = (const float*)d_in[0];
  const float* Wq = (const float*)d_in[1];
  const float* Wk = (const float*)d_in[2];
  const float* Wv = (const float*)d_in[3];
  const float* cK = (const float*)d_in[4];
  const float* cV = (const float*)d_in[5];
  const int*   Pp = (const int*)d_in[6];
  float* out = (float*)d_out;

  // ws layout (fp16): Xh 16M | Wt 32M | Qh 16M | KCh 32M | VTh 32M = 128 MiB
  if (ws_size < (size_t)134217728) return;  // visible failure instead of OOB
  char* ws = (char*)d_ws;
  f16* Xh  = (f16*)(ws);
  f16* Wt  = (f16*)(ws + (size_t)16 * 1024 * 1024);
  f16* Qh  = (f16*)(ws + (size_t)48 * 1024 * 1024);
  f16* KCh = (f16*)(ws + (size_t)64 * 1024 * 1024);
  f16* VTh = (f16*)(ws + (size_t)96 * 1024 * 1024);

  cast_kernel<<<2048, 256, 0, stream>>>(X, Xh, (long)(SEQ * NMODEL / 8));
  cast_kernel<<<2048, 256, 0, stream>>>(cK, KCh, (long)(HHEADS * MCACHE * DHEAD / 8));
  transpose_cast_kernel<<<dim3(MCACHE / 64, DHEAD / 64, HHEADS), 256, 0, stream>>>(
      cV, VTh, MCACHE, DHEAD, (long)MCACHE * DHEAD, (long)DHEAD * MCACHE);

  transpose_cast_kernel<<<dim3(64, 64, 1), 256, 0, stream>>>(Wq, Wt, NMODEL, NMODEL, 0, 0);
  gemm_kernel<0><<<dim3(SEQ / 128, NMODEL / 128), 256, 0, stream>>>(Xh, Wt, Qh, Pp);

  transpose_cast_kernel<<<dim3(64, 64, 1), 256, 0, stream>>>(Wk, Wt, NMODEL, NMODEL, 0, 0);
  gemm_kernel<1><<<dim3(SEQ / 128, NMODEL / 128), 256, 0, stream>>>(Xh, Wt, KCh, Pp);

  transpose_cast_kernel<<<dim3(64, 64, 1), 256, 0, stream>>>(Wv, Wt, NMODEL, NMODEL, 0, 0);
  gemm_kernel<2><<<dim3(NMODEL / 128, SEQ / 128), 256, 0, stream>>>(Wt, Xh, VTh, Pp);

  attn_kernel<<<dim3(SEQ / 128, HHEADS), 256, 0, stream>>>(Qh, KCh, VTh, out);
}

// Round 3
// 801.373 us; speedup vs baseline: 1.3076x; 1.3076x over previous
//
#include <hip/hip_runtime.h>

typedef _Float16 f16;
typedef _Float16 f16x8 __attribute__((ext_vector_type(8)));
typedef _Float16 f16x4 __attribute__((ext_vector_type(4)));
typedef _Float16 f16x2 __attribute__((ext_vector_type(2)));
typedef float f32x4 __attribute__((ext_vector_type(4)));
typedef float f32x16 __attribute__((ext_vector_type(16)));

#define SEQ    2048
#define NMODEL 4096
#define DHEAD  128
#define HHEADS 32
#define MCACHE 4096
#define LOG2E  1.44269504f

// ---------------------------------------------------------------- helpers
__device__ __forceinline__ void glds16(const f16* g, f16* l) {
  __builtin_amdgcn_global_load_lds((const __attribute__((address_space(1))) void*)g,
                                   (__attribute__((address_space(3))) void*)l,
                                   16, 0, 0);
}

__device__ __forceinline__ f32x16 zero16() {
  f32x16 z;
#pragma unroll
  for (int i = 0; i < 16; ++i) z[i] = 0.f;
  return z;
}

// ---------------------------------------------------------------- cast f32 -> f16 (8 elems/thread)
__global__ __launch_bounds__(256) void cast_kernel(const float* __restrict__ in,
                                                   f16* __restrict__ out, long n8) {
  long i = (long)blockIdx.x * 256 + threadIdx.x;
  const long stride = (long)gridDim.x * 256;
  for (; i < n8; i += stride) {
    const float4* p = (const float4*)(in + i * 8);
    const float4 a = p[0], b = p[1];
    f16x8 h;
    h[0] = (f16)a.x; h[1] = (f16)a.y; h[2] = (f16)a.z; h[3] = (f16)a.w;
    h[4] = (f16)b.x; h[5] = (f16)b.y; h[6] = (f16)b.z; h[7] = (f16)b.w;
    *(f16x8*)(out + i * 8) = h;
  }
}

// ---------------------------------------------------------------- tiled transpose-cast: in f32 [R][C] -> out f16 [C][R]
__global__ __launch_bounds__(256) void transpose_cast_kernel(const float* __restrict__ in,
                                                             f16* __restrict__ out,
                                                             int R, int C,
                                                             long inBatch, long outBatch) {
  __shared__ float tile[64][65];
  const int tid = threadIdx.x;
  const int r0 = blockIdx.x * 64, c0 = blockIdx.y * 64;
  in  += (size_t)blockIdx.z * inBatch;
  out += (size_t)blockIdx.z * outBatch;
#pragma unroll
  for (int p = 0; p < 4; ++p) {
    const int row = p * 16 + (tid >> 4);
    const int q = tid & 15;
    const float4 v = *(const float4*)&in[(size_t)(r0 + row) * C + c0 + q * 4];
    tile[row][q * 4 + 0] = v.x; tile[row][q * 4 + 1] = v.y;
    tile[row][q * 4 + 2] = v.z; tile[row][q * 4 + 3] = v.w;
  }
  __syncthreads();
#pragma unroll
  for (int p = 0; p < 4; ++p) {
    const int crow = p * 16 + (tid >> 4);
    const int q = tid & 15;
    f16x4 hv;
    hv[0] = (f16)tile[q * 4 + 0][crow];
    hv[1] = (f16)tile[q * 4 + 1][crow];
    hv[2] = (f16)tile[q * 4 + 2][crow];
    hv[3] = (f16)tile[q * 4 + 3][crow];
    *(f16x4*)&out[(size_t)(c0 + crow) * R + r0 + q * 4] = hv;
  }
}

// ---------------------------------------------------------------- fp16 GEMM, m97 structure (128x128 tile, BK=32, 4 waves)
// MODE 0: out = Qh[s][n] * LOG2E   MODE 1: out = KCh[h][P+s][d]   MODE 2: out = VTh[h][d][P+s]
template<int MODE>
__global__ __launch_bounds__(256) void gemm_kernel(const f16* __restrict__ A,
                                                   const f16* __restrict__ B,
                                                   f16* __restrict__ out,
                                                   const int* __restrict__ Pptr) {
  __shared__ __align__(16) f16 Ash[128 * 32];
  __shared__ __align__(16) f16 Bsh[128 * 32];
  const int tid = threadIdx.x;
  const int lane = tid & 63;
  const int w = tid >> 6;
  const int wr = w >> 1, wc = w & 1;
  const int c = lane & 15, g = lane >> 4;
  // T1 XCD-aware swizzle (nwg = 512, divisible by 8)
  const int flat = blockIdx.y * gridDim.x + blockIdx.x;
  const int nwg = gridDim.x * gridDim.y;
  const int swz = (flat & 7) * (nwg >> 3) + (flat >> 3);
  const int bx = swz % gridDim.x, by = swz / gridDim.x;
  const size_t rowA = (size_t)bx * 128;
  const size_t rowB = (size_t)by * 128;

  f32x4 acc[4][4] = {};

  const int r0 = tid >> 2;            // 0..63
  const int qq = tid & 3;             // 16B chunk within a 64B row
  const int r1 = r0 + 64;

  for (int kt = 0; kt < NMODEL / 32; ++kt) {
    const int k0 = kt * 32;
    __syncthreads();
    glds16(&A[(rowA + r0) * NMODEL + k0 + qq * 8], &Ash[(size_t)tid * 8]);
    glds16(&A[(rowA + r1) * NMODEL + k0 + qq * 8], &Ash[(size_t)(tid + 256) * 8]);
    glds16(&B[(rowB + r0) * NMODEL + k0 + qq * 8], &Bsh[(size_t)tid * 8]);
    glds16(&B[(rowB + r1) * NMODEL + k0 + qq * 8], &Bsh[(size_t)(tid + 256) * 8]);
    __syncthreads();
    f16x8 af[4], bf[4];
#pragma unroll
    for (int f = 0; f < 4; ++f)
      af[f] = *(const f16x8*)&Ash[(wr * 64 + f * 16 + c) * 32 + g * 8];
#pragma unroll
    for (int f = 0; f < 4; ++f)
      bf[f] = *(const f16x8*)&Bsh[(wc * 64 + f * 16 + c) * 32 + g * 8];
#pragma unroll
    for (int i = 0; i < 4; ++i)
#pragma unroll
      for (int j = 0; j < 4; ++j)
        acc[i][j] = __builtin_amdgcn_mfma_f32_16x16x32_f16(af[i], bf[j], acc[i][j], 0, 0, 0);
  }

  int Pv = 0;
  if (MODE != 0) Pv = *Pptr;
#pragma unroll
  for (int i = 0; i < 4; ++i)
#pragma unroll
    for (int j = 0; j < 4; ++j)
#pragma unroll
      for (int r = 0; r < 4; ++r) {
        const size_t mi = rowA + wr * 64 + i * 16 + g * 4 + r;
        const size_t ni = rowB + wc * 64 + j * 16 + c;
        if (MODE == 0) {
          out[mi * NMODEL + ni] = (f16)(acc[i][j][r] * LOG2E);  // pre-scale Q for exp2 softmax
        } else if (MODE == 1) {
          const size_t h = ni >> 7, d = ni & 127;
          out[(h * MCACHE + (size_t)Pv + mi) * DHEAD + d] = (f16)acc[i][j][r];
        } else {
          const size_t h = mi >> 7, d = mi & 127;
          out[(h * DHEAD + d) * MCACHE + (size_t)Pv + ni] = (f16)acc[i][j][r];
        }
      }
}

// ---------------------------------------------------------------- flash attention, 32x32 swapped-QK^T structure
// Qh [S][4096] f16 (pre-scaled by log2e), KC [H][M][D] f16, VT [H][D][M] f16, out f32 [H][S][D]
// Per block: 128 q-rows (4 waves x 32). Per wave: each lane owns q-row = q0+w*32+(lane&31).
// sc = mfma(K,Q): D[kv][q], col=lane&31=q, row=(r&3)+8*(r>>2)+4*h5.
// PV: O^T = mfma(V^T, P): D[d][q], per-lane scalar m/l/rescale.
__global__ __launch_bounds__(256, 2) void attn_kernel(const f16* __restrict__ Qh,
                                                      const f16* __restrict__ KC,
                                                      const f16* __restrict__ VT,
                                                      float* __restrict__ out) {
  __shared__ __align__(16) f16 Ks[64 * 128];   // [kv][d], XOR-swizzled  (byte ^= (row&7)<<4)
  __shared__ __align__(16) f16 Vs[128 * 64];   // [d][kv], XOR-swizzled
  const int tid = threadIdx.x;
  const int lane = tid & 63, w = tid >> 6;
  const int c5 = lane & 31, h5 = lane >> 5;
  const int cx = (c5 & 7) << 4;

  // T1: XCD swizzle — 4 consecutive heads per XCD (nwg=512)
  const int flat = blockIdx.x;
  const int swz = (flat & 7) * 64 + (flat >> 3);
  const int h = swz >> 4, qc = swz & 15;
  const int qrow = qc * 128 + w * 32 + c5;

  const f16* Kb = KC + (size_t)h * (MCACHE * DHEAD);
  const f16* Vb = VT + (size_t)h * (DHEAD * MCACHE);

  // Q fragments: B-operand, col=q=c5, k = kg*16 + h5*8 + j
  f16x8 qf[8];
#pragma unroll
  for (int kg = 0; kg < 8; ++kg)
    qf[kg] = *(const f16x8*)&Qh[(size_t)qrow * NMODEL + h * DHEAD + kg * 16 + h5 * 8];

  f32x16 accO[4];
#pragma unroll
  for (int df = 0; df < 4; ++df) accO[df] = zero16();
  float m = -1e30f, l = 0.f;

  // staging: thread t stages 64B of K (row t>>2) and 64B of V (row t>>1)
  const int kRow = tid >> 2, kCol = (tid & 3) * 32;       // K elem offsets
  const int vRow = tid >> 1, vCol = (tid & 1) * 32;       // V elem offsets
  char* KsB = (char*)Ks;
  char* VsB = (char*)Vs;
  const int ksBase = kRow * 256 + (tid & 3) * 64, ksX = (kRow & 7) << 4;
  const int vsBase = vRow * 128 + (tid & 1) * 64, vsX = (vRow & 7) << 4;

  f16x8 G[8];
  {
    const f16* kp = Kb + (size_t)kRow * DHEAD + kCol;
    const f16* vp = Vb + (size_t)vRow * MCACHE + vCol;
#pragma unroll
    for (int i = 0; i < 4; ++i) G[i] = *(const f16x8*)(kp + i * 8);
#pragma unroll
    for (int i = 0; i < 4; ++i) G[4 + i] = *(const f16x8*)(vp + i * 8);
  }

  const int NT = MCACHE / 64;
  for (int t = 0; t < NT; ++t) {
    __syncthreads();                       // prior tile fully consumed
    // T14: write staged regs, then immediately issue next tile's loads
#pragma unroll
    for (int i = 0; i < 4; ++i) *(f16x8*)(KsB + ((ksBase + i * 16) ^ ksX)) = G[i];
#pragma unroll
    for (int i = 0; i < 4; ++i) *(f16x8*)(VsB + ((vsBase + i * 16) ^ vsX)) = G[4 + i];
    if (t + 1 < NT) {
      const f16* kp = Kb + (size_t)(t + 1) * 64 * DHEAD + (size_t)kRow * DHEAD + kCol;
      const f16* vp = Vb + (size_t)vRow * MCACHE + (t + 1) * 64 + vCol;
#pragma unroll
      for (int i = 0; i < 4; ++i) G[i] = *(const f16x8*)(kp + i * 8);
#pragma unroll
      for (int i = 0; i < 4; ++i) G[4 + i] = *(const f16x8*)(vp + i * 8);
    }
    __syncthreads();                       // staged LDS visible

    // ---- QK^T (swapped): sc[kvf] = K-rows(kvf*32+c5) x Q
    f32x16 sc0 = zero16(), sc1 = zero16();
    __builtin_amdgcn_s_setprio(1);
#pragma unroll
    for (int kg = 0; kg < 8; ++kg) {
      const f16x8 kb0 = *(const f16x8*)(KsB + ((c5 * 256 + kg * 32 + h5 * 16) ^ cx));
      const f16x8 kb1 = *(const f16x8*)(KsB + (((32 + c5) * 256 + kg * 32 + h5 * 16) ^ cx));
      sc0 = __builtin_amdgcn_mfma_f32_32x32x16_f16(kb0, qf[kg], sc0, 0, 0, 0);
      sc1 = __builtin_amdgcn_mfma_f32_32x32x16_f16(kb1, qf[kg], sc1, 0, 0, 0);
    }
    __builtin_amdgcn_s_setprio(0);

    // ---- online softmax: each lane owns one q-row; 32 in-lane + cross-half
    float pm = sc0[0];
#pragma unroll
    for (int r = 1; r < 16; ++r) pm = fmaxf(pm, sc0[r]);
#pragma unroll
    for (int r = 0; r < 16; ++r) pm = fmaxf(pm, sc1[r]);
    pm = fmaxf(pm, __shfl_xor(pm, 32));
    if (__any(pm > m + 11.0f)) {           // T13 defer-max (base-2 threshold)
      const float mn = fmaxf(m, pm);
      const float sca = exp2f(m - mn);
#pragma unroll
      for (int df = 0; df < 4; ++df)
#pragma unroll
        for (int r = 0; r < 16; ++r) accO[df][r] *= sca;
      l *= sca;
      m = mn;
    }
    float rs = 0.f;
#pragma unroll
    for (int r = 0; r < 16; ++r) { const float e = exp2f(sc0[r] - m); sc0[r] = e; rs += e; }
#pragma unroll
    for (int r = 0; r < 16; ++r) { const float e = exp2f(sc1[r] - m); sc1[r] = e; rs += e; }
    rs += __shfl_xor(rs, 32);
    l += rs;

    // ---- T12: P -> fp16 B-fragments in-register (cvt_pkrtz + permlane32_swap)
    // target pa[kg] elem (h5,j): P[q=c5][kv = kg*16 + h5*8 + j]
    // source: sc(kvf=kg>>1) reg r holds kv-local = (r&3) + 4*h5 + 8*(r>>2)
    f16x8 pa[4];
#pragma unroll
    for (int kg = 0; kg < 4; ++kg) {
      union { unsigned u[4]; f16x8 v; } pw;
#pragma unroll
      for (int v2 = 0; v2 < 2; ++v2) {
        const int r0 = (kg & 1) * 8 + 2 * v2;
        float a0, a1, b0, b1;
        if (kg < 2) { a0 = sc0[r0]; a1 = sc0[r0 + 1]; b0 = sc0[r0 + 4]; b1 = sc0[r0 + 5]; }
        else        { a0 = sc1[r0]; a1 = sc1[r0 + 1]; b0 = sc1[r0 + 4]; b1 = sc1[r0 + 5]; }
        unsigned U = __builtin_bit_cast(unsigned, __builtin_amdgcn_cvt_pkrtz(a0, a1));
        unsigned W = __builtin_bit_cast(unsigned, __builtin_amdgcn_cvt_pkrtz(b0, b1));
        // U' = {U_lo, W_lo} (word v2 for all lanes), W' = {U_hi, W_hi} (word 2+v2)
        asm("v_permlane32_swap_b32 %0, %1" : "+v"(U), "+v"(W));
        pw.u[v2] = U;
        pw.u[2 + v2] = W;
      }
      pa[kg] = pw.v;
    }

    // ---- PV: O^T[d][q] += V^T[d][kv] * P[q][kv]
    __builtin_amdgcn_s_setprio(1);
#pragma unroll
    for (int df = 0; df < 4; ++df) {
      const int drow = df * 32 + c5;
#pragma unroll
      for (int kg = 0; kg < 4; ++kg) {
        const f16x8 vb = *(const f16x8*)(VsB + ((drow * 128 + kg * 32 + h5 * 16) ^ cx));
        accO[df] = __builtin_amdgcn_mfma_f32_32x32x16_f16(vb, pa[kg], accO[df], 0, 0, 0);
      }
    }
    __builtin_amdgcn_s_setprio(0);
  }

  // ---- epilogue: out[h][q][d] = accO^T / l ; lane owns row q=qrow, 64 d-values
  const float invl = 1.0f / l;
  float* orow = out + ((size_t)h * SEQ + qrow) * DHEAD;
#pragma unroll
  for (int df = 0; df < 4; ++df)
#pragma unroll
    for (int rq = 0; rq < 4; ++rq) {
      float4 o;
      o.x = accO[df][rq * 4 + 0] * invl;
      o.y = accO[df][rq * 4 + 1] * invl;
      o.z = accO[df][rq * 4 + 2] * invl;
      o.w = accO[df][rq * 4 + 3] * invl;
      *(float4*)(orow + df * 32 + rq * 8 + h5 * 4) = o;
    }
}

// ---------------------------------------------------------------- launch
extern "C" void kernel_launch(void* const* d_in, const int* in_sizes, int n_in,
                              void* d_out, int out_size, void* d_ws, size_t ws_size,
                              hipStream_t stream) {
  (void)in_sizes; (void)n_in; (void)out_size;
  const float* X  = (const float*)d_in[0];
  const float* Wq = (const float*)d_in[1];
  const float* Wk = (const float*)d_in[2];
  const float* Wv = (const float*)d_in[3];
  const float* cK = (const float*)d_in[4];
  const float* cV = (const float*)d_in[5];
  const int*   Pp = (const int*)d_in[6];
  float* out = (float*)d_out;

  // ws layout (fp16): Xh 16M | Wt 32M | Qh 16M | KCh 32M | VTh 32M = 128 MiB
  if (ws_size < (size_t)134217728) return;
  char* ws = (char*)d_ws;
  f16* Xh  = (f16*)(ws);
  f16* Wt  = (f16*)(ws + (size_t)16 * 1024 * 1024);
  f16* Qh  = (f16*)(ws + (size_t)48 * 1024 * 1024);
  f16* KCh = (f16*)(ws + (size_t)64 * 1024 * 1024);
  f16* VTh = (f16*)(ws + (size_t)96 * 1024 * 1024);

  cast_kernel<<<2048, 256, 0, stream>>>(X, Xh, (long)(SEQ * NMODEL / 8));
  cast_kernel<<<2048, 256, 0, stream>>>(cK, KCh, (long)(HHEADS * MCACHE * DHEAD / 8));
  transpose_cast_kernel<<<dim3(MCACHE / 64, DHEAD / 64, HHEADS), 256, 0, stream>>>(
      cV, VTh, MCACHE, DHEAD, (long)MCACHE * DHEAD, (long)DHEAD * MCACHE);

  transpose_cast_kernel<<<dim3(64, 64, 1), 256, 0, stream>>>(Wq, Wt, NMODEL, NMODEL, 0, 0);
  gemm_kernel<0><<<dim3(SEQ / 128, NMODEL / 128), 256, 0, stream>>>(Xh, Wt, Qh, Pp);

  transpose_cast_kernel<<<dim3(64, 64, 1), 256, 0, stream>>>(Wk, Wt, NMODEL, NMODEL, 0, 0);
  gemm_kernel<1><<<dim3(SEQ / 128, NMODEL / 128), 256, 0, stream>>>(Xh, Wt, KCh, Pp);

  transpose_cast_kernel<<<dim3(64, 64, 1), 256, 0, stream>>>(Wv, Wt, NMODEL, NMODEL, 0, 0);
  gemm_kernel<2><<<dim3(NMODEL / 128, SEQ / 128), 256, 0, stream>>>(Wt, Xh, VTh, Pp);

  attn_kernel<<<512, 256, 0, stream>>>(Qh, KCh, VTh, out);
}

// Round 5
// 775.421 us; speedup vs baseline: 1.3513x; 1.0335x over previous
//
#include <hip/hip_runtime.h>

typedef _Float16 f16;
typedef _Float16 f16x8 __attribute__((ext_vector_type(8)));
typedef _Float16 f16x4 __attribute__((ext_vector_type(4)));
typedef float f32x4 __attribute__((ext_vector_type(4)));
typedef float f32x16 __attribute__((ext_vector_type(16)));

#define SEQ    2048
#define NMODEL 4096
#define DHEAD  128
#define HHEADS 32
#define MCACHE 4096
#define LOG2E  1.44269504f

// ---------------------------------------------------------------- helpers
__device__ __forceinline__ void glds16(const f16* g, f16* l) {
  __builtin_amdgcn_global_load_lds((const __attribute__((address_space(1))) void*)g,
                                   (__attribute__((address_space(3))) void*)l,
                                   16, 0, 0);
}

__device__ __forceinline__ f32x16 zero16() {
  f32x16 z;
#pragma unroll
  for (int i = 0; i < 16; ++i) z[i] = 0.f;
  return z;
}

// ---------------------------------------------------------------- cast f32 -> f16 (8 elems/thread)
__global__ __launch_bounds__(256) void cast_kernel(const float* __restrict__ in,
                                                   f16* __restrict__ out, long n8) {
  long i = (long)blockIdx.x * 256 + threadIdx.x;
  const long stride = (long)gridDim.x * 256;
  for (; i < n8; i += stride) {
    const float4* p = (const float4*)(in + i * 8);
    const float4 a = p[0], b = p[1];
    f16x8 h;
    h[0] = (f16)a.x; h[1] = (f16)a.y; h[2] = (f16)a.z; h[3] = (f16)a.w;
    h[4] = (f16)b.x; h[5] = (f16)b.y; h[6] = (f16)b.z; h[7] = (f16)b.w;
    *(f16x8*)(out + i * 8) = h;
  }
}

// ---------------------------------------------------------------- tiled transpose-cast: in f32 [R][C] -> out f16 [C][R]
__global__ __launch_bounds__(256) void transpose_cast_kernel(const float* __restrict__ in,
                                                             f16* __restrict__ out,
                                                             int R, int C,
                                                             long inBatch, long outBatch) {
  __shared__ float tile[64][65];
  const int tid = threadIdx.x;
  const int r0 = blockIdx.x * 64, c0 = blockIdx.y * 64;
  in  += (size_t)blockIdx.z * inBatch;
  out += (size_t)blockIdx.z * outBatch;
#pragma unroll
  for (int p = 0; p < 4; ++p) {
    const int row = p * 16 + (tid >> 4);
    const int q = tid & 15;
    const float4 v = *(const float4*)&in[(size_t)(r0 + row) * C + c0 + q * 4];
    tile[row][q * 4 + 0] = v.x; tile[row][q * 4 + 1] = v.y;
    tile[row][q * 4 + 2] = v.z; tile[row][q * 4 + 3] = v.w;
  }
  __syncthreads();
#pragma unroll
  for (int p = 0; p < 4; ++p) {
    const int crow = p * 16 + (tid >> 4);
    const int q = tid & 15;
    f16x4 hv;
    hv[0] = (f16)tile[q * 4 + 0][crow];
    hv[1] = (f16)tile[q * 4 + 1][crow];
    hv[2] = (f16)tile[q * 4 + 2][crow];
    hv[3] = (f16)tile[q * 4 + 3][crow];
    *(f16x4*)&out[(size_t)(c0 + crow) * R + r0 + q * 4] = hv;
  }
}

// ---------------------------------------------------------------- FUSED QKV GEMM (m97 structure, 128x128 tile, BK=32)
// A = Xh [2048][4096] k-major. Wt = [12288][4096] k-major ([Wq^T;Wk^T;Wv^T]).
// Grid (16, 96). Epilogue routes by sel = rowB>>12: 0->Qh (x LOG2E), 1->K cache scatter, 2->V^T scatter.
__global__ __launch_bounds__(256) void gemm_qkv_kernel(const f16* __restrict__ A,
                                                       const f16* __restrict__ Wt,
                                                       f16* __restrict__ Qh,
                                                       f16* __restrict__ KCh,
                                                       f16* __restrict__ VTh,
                                                       const int* __restrict__ Pptr) {
  __shared__ __align__(16) f16 Ash[128 * 32];
  __shared__ __align__(16) f16 Bsh[128 * 32];
  const int tid = threadIdx.x;
  const int lane = tid & 63;
  const int w = tid >> 6;
  const int wr = w >> 1, wc = w & 1;
  const int c = lane & 15, g = lane >> 4;
  // T1 XCD swizzle: nwg = 1536, divisible by 8
  const int flat = blockIdx.y * gridDim.x + blockIdx.x;
  const int nwg = gridDim.x * gridDim.y;
  const int swz = (flat & 7) * (nwg >> 3) + (flat >> 3);
  const int bx = swz % gridDim.x, by = swz / gridDim.x;
  const size_t rowA = (size_t)bx * 128;
  const size_t rowB = (size_t)by * 128;

  f32x4 acc[4][4] = {};

  const int r0 = tid >> 2;            // 0..63
  const int qq = tid & 3;             // 16B chunk within a 64B row
  const int r1 = r0 + 64;

  for (int kt = 0; kt < NMODEL / 32; ++kt) {
    const int k0 = kt * 32;
    __syncthreads();
    glds16(&A[(rowA + r0) * NMODEL + k0 + qq * 8], &Ash[(size_t)tid * 8]);
    glds16(&A[(rowA + r1) * NMODEL + k0 + qq * 8], &Ash[(size_t)(tid + 256) * 8]);
    glds16(&Wt[(rowB + r0) * NMODEL + k0 + qq * 8], &Bsh[(size_t)tid * 8]);
    glds16(&Wt[(rowB + r1) * NMODEL + k0 + qq * 8], &Bsh[(size_t)(tid + 256) * 8]);
    __syncthreads();
    f16x8 af[4], bf[4];
#pragma unroll
    for (int f = 0; f < 4; ++f)
      af[f] = *(const f16x8*)&Ash[(wr * 64 + f * 16 + c) * 32 + g * 8];
#pragma unroll
    for (int f = 0; f < 4; ++f)
      bf[f] = *(const f16x8*)&Bsh[(wc * 64 + f * 16 + c) * 32 + g * 8];
#pragma unroll
    for (int i = 0; i < 4; ++i)
#pragma unroll
      for (int j = 0; j < 4; ++j)
        acc[i][j] = __builtin_amdgcn_mfma_f32_16x16x32_f16(af[i], bf[j], acc[i][j], 0, 0, 0);
  }

  const int sel = (int)(rowB >> 12);          // 0=Q, 1=K, 2=V (block-uniform)
  const int Pv = *Pptr;
#pragma unroll
  for (int i = 0; i < 4; ++i)
#pragma unroll
    for (int j = 0; j < 4; ++j) {
      const size_t mib = rowA + wr * 64 + i * 16 + g * 4;   // r=0 row
      const size_t ni = rowB + wc * 64 + j * 16 + c;
      const size_t nloc = ni & 4095;
      if (sel == 2) {
        // V^T: contiguous along mi -> vectorized 4 x f16
        f16x4 v4;
#pragma unroll
        for (int r = 0; r < 4; ++r) v4[r] = (f16)acc[i][j][r];
        *(f16x4*)&VTh[nloc * MCACHE + (size_t)Pv + mib] = v4;
      } else if (sel == 0) {
#pragma unroll
        for (int r = 0; r < 4; ++r)
          Qh[(mib + r) * NMODEL + nloc] = (f16)(acc[i][j][r] * LOG2E);
      } else {
        const size_t h = nloc >> 7, d = nloc & 127;
#pragma unroll
        for (int r = 0; r < 4; ++r)
          KCh[(h * MCACHE + (size_t)Pv + mib + r) * DHEAD + d] = (f16)acc[i][j][r];
      }
    }
}

// ---------------------------------------------------------------- sequential-fallback GEMM (ws too small for fused)
template<int MODE>
__global__ __launch_bounds__(256) void gemm_kernel(const f16* __restrict__ A,
                                                   const f16* __restrict__ B,
                                                   f16* __restrict__ out,
                                                   const int* __restrict__ Pptr) {
  __shared__ __align__(16) f16 Ash[128 * 32];
  __shared__ __align__(16) f16 Bsh[128 * 32];
  const int tid = threadIdx.x;
  const int lane = tid & 63;
  const int w = tid >> 6;
  const int wr = w >> 1, wc = w & 1;
  const int c = lane & 15, g = lane >> 4;
  const int flat = blockIdx.y * gridDim.x + blockIdx.x;
  const int nwg = gridDim.x * gridDim.y;
  const int swz = (flat & 7) * (nwg >> 3) + (flat >> 3);
  const int bx = swz % gridDim.x, by = swz / gridDim.x;
  const size_t rowA = (size_t)bx * 128;
  const size_t rowB = (size_t)by * 128;

  f32x4 acc[4][4] = {};
  const int r0 = tid >> 2;
  const int qq = tid & 3;
  const int r1 = r0 + 64;

  for (int kt = 0; kt < NMODEL / 32; ++kt) {
    const int k0 = kt * 32;
    __syncthreads();
    glds16(&A[(rowA + r0) * NMODEL + k0 + qq * 8], &Ash[(size_t)tid * 8]);
    glds16(&A[(rowA + r1) * NMODEL + k0 + qq * 8], &Ash[(size_t)(tid + 256) * 8]);
    glds16(&B[(rowB + r0) * NMODEL + k0 + qq * 8], &Bsh[(size_t)tid * 8]);
    glds16(&B[(rowB + r1) * NMODEL + k0 + qq * 8], &Bsh[(size_t)(tid + 256) * 8]);
    __syncthreads();
    f16x8 af[4], bf[4];
#pragma unroll
    for (int f = 0; f < 4; ++f)
      af[f] = *(const f16x8*)&Ash[(wr * 64 + f * 16 + c) * 32 + g * 8];
#pragma unroll
    for (int f = 0; f < 4; ++f)
      bf[f] = *(const f16x8*)&Bsh[(wc * 64 + f * 16 + c) * 32 + g * 8];
#pragma unroll
    for (int i = 0; i < 4; ++i)
#pragma unroll
      for (int j = 0; j < 4; ++j)
        acc[i][j] = __builtin_amdgcn_mfma_f32_16x16x32_f16(af[i], bf[j], acc[i][j], 0, 0, 0);
  }

  int Pv = 0;
  if (MODE != 0) Pv = *Pptr;
#pragma unroll
  for (int i = 0; i < 4; ++i)
#pragma unroll
    for (int j = 0; j < 4; ++j)
#pragma unroll
      for (int r = 0; r < 4; ++r) {
        const size_t mi = rowA + wr * 64 + i * 16 + g * 4 + r;
        const size_t ni = rowB + wc * 64 + j * 16 + c;
        if (MODE == 0) {
          out[mi * NMODEL + ni] = (f16)(acc[i][j][r] * LOG2E);
        } else if (MODE == 1) {
          const size_t h = ni >> 7, d = ni & 127;
          out[(h * MCACHE + (size_t)Pv + mi) * DHEAD + d] = (f16)acc[i][j][r];
        } else {
          const size_t h = mi >> 7, d = mi & 127;
          out[(h * DHEAD + d) * MCACHE + (size_t)Pv + ni] = (f16)acc[i][j][r];
        }
      }
}

// ---------------------------------------------------------------- flash attention, 32x32 swapped-QK^T structure
__global__ __launch_bounds__(256, 2) void attn_kernel(const f16* __restrict__ Qh,
                                                      const f16* __restrict__ KC,
                                                      const f16* __restrict__ VT,
                                                      float* __restrict__ out) {
  __shared__ __align__(16) f16 Ks[64 * 128];   // [kv][d], XOR-swizzled
  __shared__ __align__(16) f16 Vs[128 * 64];   // [d][kv], XOR-swizzled
  const int tid = threadIdx.x;
  const int lane = tid & 63, w = tid >> 6;
  const int c5 = lane & 31, h5 = lane >> 5;
  const int cx = (c5 & 7) << 4;

  const int flat = blockIdx.x;
  const int swz = (flat & 7) * 64 + (flat >> 3);
  const int h = swz >> 4, qc = swz & 15;
  const int qrow = qc * 128 + w * 32 + c5;

  const f16* Kb = KC + (size_t)h * (MCACHE * DHEAD);
  const f16* Vb = VT + (size_t)h * (DHEAD * MCACHE);

  f16x8 qf[8];
#pragma unroll
  for (int kg = 0; kg < 8; ++kg)
    qf[kg] = *(const f16x8*)&Qh[(size_t)qrow * NMODEL + h * DHEAD + kg * 16 + h5 * 8];

  f32x16 accO[4];
#pragma unroll
  for (int df = 0; df < 4; ++df) accO[df] = zero16();
  float m = -1e30f, l = 0.f;

  const int kRow = tid >> 2, kCol = (tid & 3) * 32;
  const int vRow = tid >> 1, vCol = (tid & 1) * 32;
  char* KsB = (char*)Ks;
  char* VsB = (char*)Vs;
  const int ksBase = kRow * 256 + (tid & 3) * 64, ksX = (kRow & 7) << 4;
  const int vsBase = vRow * 128 + (tid & 1) * 64, vsX = (vRow & 7) << 4;

  f16x8 G[8];
  {
    const f16* kp = Kb + (size_t)kRow * DHEAD + kCol;
    const f16* vp = Vb + (size_t)vRow * MCACHE + vCol;
#pragma unroll
    for (int i = 0; i < 4; ++i) G[i] = *(const f16x8*)(kp + i * 8);
#pragma unroll
    for (int i = 0; i < 4; ++i) G[4 + i] = *(const f16x8*)(vp + i * 8);
  }

  const int NT = MCACHE / 64;
  for (int t = 0; t < NT; ++t) {
    __syncthreads();
#pragma unroll
    for (int i = 0; i < 4; ++i) *(f16x8*)(KsB + ((ksBase + i * 16) ^ ksX)) = G[i];
#pragma unroll
    for (int i = 0; i < 4; ++i) *(f16x8*)(VsB + ((vsBase + i * 16) ^ vsX)) = G[4 + i];
    if (t + 1 < NT) {
      const f16* kp = Kb + (size_t)(t + 1) * 64 * DHEAD + (size_t)kRow * DHEAD + kCol;
      const f16* vp = Vb + (size_t)vRow * MCACHE + (t + 1) * 64 + vCol;
#pragma unroll
      for (int i = 0; i < 4; ++i) G[i] = *(const f16x8*)(kp + i * 8);
#pragma unroll
      for (int i = 0; i < 4; ++i) G[4 + i] = *(const f16x8*)(vp + i * 8);
    }
    __syncthreads();

    f32x16 sc0 = zero16(), sc1 = zero16();
    __builtin_amdgcn_s_setprio(1);
#pragma unroll
    for (int kg = 0; kg < 8; ++kg) {
      const f16x8 kb0 = *(const f16x8*)(KsB + ((c5 * 256 + kg * 32 + h5 * 16) ^ cx));
      const f16x8 kb1 = *(const f16x8*)(KsB + (((32 + c5) * 256 + kg * 32 + h5 * 16) ^ cx));
      sc0 = __builtin_amdgcn_mfma_f32_32x32x16_f16(kb0, qf[kg], sc0, 0, 0, 0);
      sc1 = __builtin_amdgcn_mfma_f32_32x32x16_f16(kb1, qf[kg], sc1, 0, 0, 0);
    }
    __builtin_amdgcn_s_setprio(0);

    float pm = sc0[0];
#pragma unroll
    for (int r = 1; r < 16; ++r) pm = fmaxf(pm, sc0[r]);
#pragma unroll
    for (int r = 0; r < 16; ++r) pm = fmaxf(pm, sc1[r]);
    pm = fmaxf(pm, __shfl_xor(pm, 32));
    if (__any(pm > m + 11.0f)) {
      const float mn = fmaxf(m, pm);
      const float sca = exp2f(m - mn);
#pragma unroll
      for (int df = 0; df < 4; ++df)
#pragma unroll
        for (int r = 0; r < 16; ++r) accO[df][r] *= sca;
      l *= sca;
      m = mn;
    }
    float rs = 0.f;
#pragma unroll
    for (int r = 0; r < 16; ++r) { const float e = exp2f(sc0[r] - m); sc0[r] = e; rs += e; }
#pragma unroll
    for (int r = 0; r < 16; ++r) { const float e = exp2f(sc1[r] - m); sc1[r] = e; rs += e; }
    rs += __shfl_xor(rs, 32);
    l += rs;

    f16x8 pa[4];
#pragma unroll
    for (int kg = 0; kg < 4; ++kg) {
      union { unsigned u[4]; f16x8 v; } pw;
#pragma unroll
      for (int v2 = 0; v2 < 2; ++v2) {
        const int r0 = (kg & 1) * 8 + 2 * v2;
        float a0, a1, b0, b1;
        if (kg < 2) { a0 = sc0[r0]; a1 = sc0[r0 + 1]; b0 = sc0[r0 + 4]; b1 = sc0[r0 + 5]; }
        else        { a0 = sc1[r0]; a1 = sc1[r0 + 1]; b0 = sc1[r0 + 4]; b1 = sc1[r0 + 5]; }
        unsigned U = __builtin_bit_cast(unsigned, __builtin_amdgcn_cvt_pkrtz(a0, a1));
        unsigned W = __builtin_bit_cast(unsigned, __builtin_amdgcn_cvt_pkrtz(b0, b1));
        asm("v_permlane32_swap_b32 %0, %1" : "+v"(U), "+v"(W));
        pw.u[v2] = U;
        pw.u[2 + v2] = W;
      }
      pa[kg] = pw.v;
    }

    __builtin_amdgcn_s_setprio(1);
#pragma unroll
    for (int df = 0; df < 4; ++df) {
      const int drow = df * 32 + c5;
#pragma unroll
      for (int kg = 0; kg < 4; ++kg) {
        const f16x8 vb = *(const f16x8*)(VsB + ((drow * 128 + kg * 32 + h5 * 16) ^ cx));
        accO[df] = __builtin_amdgcn_mfma_f32_32x32x16_f16(vb, pa[kg], accO[df], 0, 0, 0);
      }
    }
    __builtin_amdgcn_s_setprio(0);
  }

  const float invl = 1.0f / l;
  float* orow = out + ((size_t)h * SEQ + qrow) * DHEAD;
#pragma unroll
  for (int df = 0; df < 4; ++df)
#pragma unroll
    for (int rq = 0; rq < 4; ++rq) {
      float4 o;
      o.x = accO[df][rq * 4 + 0] * invl;
      o.y = accO[df][rq * 4 + 1] * invl;
      o.z = accO[df][rq * 4 + 2] * invl;
      o.w = accO[df][rq * 4 + 3] * invl;
      *(float4*)(orow + df * 32 + rq * 8 + h5 * 4) = o;
    }
}

// ---------------------------------------------------------------- launch
extern "C" void kernel_launch(void* const* d_in, const int* in_sizes, int n_in,
                              void* d_out, int out_size, void* d_ws, size_t ws_size,
                              hipStream_t stream) {
  (void)in_sizes; (void)n_in; (void)out_size;
  const float* X  = (const float*)d_in[0];
  const float* Wq = (const float*)d_in[1];
  const float* Wk = (const float*)d_in[2];
  const float* Wv = (const float*)d_in[3];
  const float* cK = (const float*)d_in[4];
  const float* cV = (const float*)d_in[5];
  const int*   Pp = (const int*)d_in[6];
  float* out = (float*)d_out;

  // ws layout (fp16): Xh 16M @0 | Qh 16M @16M | KCh 32M @32M | VTh 32M @64M | Wt @96M (96M fused / 32M seq)
  const size_t MB = 1024 * 1024;
  if (ws_size < 128 * MB) return;
  char* ws = (char*)d_ws;
  f16* Xh  = (f16*)(ws);
  f16* Qh  = (f16*)(ws + 16 * MB);
  f16* KCh = (f16*)(ws + 32 * MB);
  f16* VTh = (f16*)(ws + 64 * MB);
  f16* Wt  = (f16*)(ws + 96 * MB);
  const bool fused = ws_size >= 192 * MB;

  cast_kernel<<<2048, 256, 0, stream>>>(X, Xh, (long)(SEQ * NMODEL / 8));
  cast_kernel<<<2048, 256, 0, stream>>>(cK, KCh, (long)(HHEADS * MCACHE * DHEAD / 8));
  transpose_cast_kernel<<<dim3(MCACHE / 64, DHEAD / 64, HHEADS), 256, 0, stream>>>(
      cV, VTh, MCACHE, DHEAD, (long)MCACHE * DHEAD, (long)DHEAD * MCACHE);

  if (fused) {
    const size_t WSTRIDE = (size_t)NMODEL * NMODEL;
    transpose_cast_kernel<<<dim3(64, 64, 1), 256, 0, stream>>>(Wq, Wt,               NMODEL, NMODEL, 0, 0);
    transpose_cast_kernel<<<dim3(64, 64, 1), 256, 0, stream>>>(Wk, Wt + WSTRIDE,     NMODEL, NMODEL, 0, 0);
    transpose_cast_kernel<<<dim3(64, 64, 1), 256, 0, stream>>>(Wv, Wt + 2 * WSTRIDE, NMODEL, NMODEL, 0, 0);
    gemm_qkv_kernel<<<dim3(SEQ / 128, 3 * NMODEL / 128), 256, 0, stream>>>(Xh, Wt, Qh, KCh, VTh, Pp);
  } else {
    transpose_cast_kernel<<<dim3(64, 64, 1), 256, 0, stream>>>(Wq, Wt, NMODEL, NMODEL, 0, 0);
    gemm_kernel<0><<<dim3(SEQ / 128, NMODEL / 128), 256, 0, stream>>>(Xh, Wt, Qh, Pp);
    transpose_cast_kernel<<<dim3(64, 64, 1), 256, 0, stream>>>(Wk, Wt, NMODEL, NMODEL, 0, 0);
    gemm_kernel<1><<<dim3(SEQ / 128, NMODEL / 128), 256, 0, stream>>>(Xh, Wt, KCh, Pp);
    transpose_cast_kernel<<<dim3(64, 64, 1), 256, 0, stream>>>(Wv, Wt, NMODEL, NMODEL, 0, 0);
    gemm_kernel<2><<<dim3(NMODEL / 128, SEQ / 128), 256, 0, stream>>>(Wt, Xh, VTh, Pp);
  }

  attn_kernel<<<512, 256, 0, stream>>>(Qh, KCh, VTh, out);
}